// Round 7
// baseline (27.392 us; speedup 1.0000x reference)
//
#include <hip/hip_runtime.h>

// out[b,e,t] = sum_{s<=t} x[s]*(w0[s]*dv0^(t-s) + w1[t]*dv1^(t-s)) + bias[t]
//   P[t] = dv0*P[t-1] + x[t]*w0[t];  Q[t] = dv1*Q[t-1] + x[t]
//   out[t] = P[t] + w1[t]*Q[t] + bias[t]
// Persistent-style block: 4 rows processed sequentially per 256-thread block
// (2048 blocks), software-pipelined 2-deep: row r+2's x-loads are issued at
// the top of iteration r and stay in flight across the carry barriers (raw
// s_barrier + lgkmcnt-only drain; NO sched_barrier pinning). Weights/bias
// loaded once per block. Unit-lane-stride float4 I/O. Per-row ctot LDS slots
// (no WAR, one barrier per row). Scan per row: 4-elem segment totals ->
// wave Kogge-Stone (factor dv^4, A/B chunks independent) -> 8 chunk totals
// combined from LDS (factor dv^256) -> fixup + fused epilogue.

#define S_LEN 2048
#define THREADS 256
#define RPB 4

typedef float f4 __attribute__((ext_vector_type(4)));

__global__ __launch_bounds__(THREADS, 4)
void crcl_kernel(const float* __restrict__ x,
                 const float* __restrict__ weight,
                 const float* __restrict__ bias,
                 const float* __restrict__ decay,
                 float* __restrict__ out,
                 int nrows)
{
    __shared__ float ctot[RPB][2][8];   // [row][p/q][chunk]

    const int t    = (int)threadIdx.x;
    const int lane = t & 63;
    const int w    = t >> 6;
    const long row0 = (long)blockIdx.x * RPB;
    const int sA = t, sB = 256 + t;     // owned f4 segments (unit lane stride)

    // ---- block-invariant arrays: loaded ONCE per block ----
    const f4* w04 = (const f4*)weight;            // weight[0][:]
    const f4* w14 = (const f4*)(weight + S_LEN);  // weight[1][:]
    const f4* b4  = (const f4*)bias;
    const f4 wA = w04[sA], wB = w04[sB];
    const f4 vA = w14[sA], vB = w14[sB];
    const f4 bA = b4[sA],  bB = b4[sB];

    const float dv0 = fminf(fmaxf(decay[0], 0.9f), 1.0f);
    const float dv1 = fminf(fmaxf(decay[1], 0.9f), 1.0f);

    float A4_0 = dv0 * dv0; A4_0 *= A4_0;          // dv0^4
    float A4_1 = dv1 * dv1; A4_1 *= A4_1;          // dv1^4
    float A256_0 = A4_0, A256_1 = A4_1;            // dv^256
#pragma unroll
    for (int b = 0; b < 6; ++b) { A256_0 *= A256_0; A256_1 *= A256_1; }
    const float e4 = (float)(4 * lane);
    const float pw0l = exp2f(e4 * log2f(dv0));     // dv0^(4*lane)
    const float pw1l = exp2f(e4 * log2f(dv1));

    // ---- prologue: rows 0 and 1 in flight ----
    long r0c = row0;     if (r0c >= nrows) r0c = nrows - 1;
    long r1c = row0 + 1; if (r1c >= nrows) r1c = nrows - 1;
    const f4* xp0 = (const f4*)(x + r0c * (long)S_LEN);
    const f4* xp1 = (const f4*)(x + r1c * (long)S_LEN);
    f4 cxA = xp0[sA], cxB = xp0[sB];
    f4 nxA = xp1[sA], nxB = xp1[sB];

#pragma unroll
    for (int r = 0; r < RPB; ++r) {
        // ---- prefetch row r+2 (consumed 2 iterations / 2 barriers later) ----
        f4 pxA, pxB;
        if (r + 2 < RPB) {
            long rp = row0 + r + 2; if (rp >= nrows) rp = nrows - 1;
            const f4* xp = (const f4*)(x + rp * (long)S_LEN);
            pxA = xp[sA]; pxB = xp[sB];
        }

        // ---- pass 1: per-segment totals ----
        float TAp = 0.0f, TAq = 0.0f, TBp = 0.0f, TBq = 0.0f;
#pragma unroll
        for (int j = 0; j < 4; ++j) {
            TAp = fmaf(dv0, TAp, cxA[j] * wA[j]);
            TAq = fmaf(dv1, TAq, cxA[j]);
            TBp = fmaf(dv0, TBp, cxB[j] * wB[j]);
            TBq = fmaf(dv1, TBq, cxB[j]);
        }

        // ---- wave Kogge-Stone, factor dv^4, A/B independent ----
        float sAp = TAp, sAq = TAq, sBp = TBp, sBq = TBq;
        float k0 = A4_0, k1 = A4_1;
#pragma unroll
        for (int d = 1; d < 64; d <<= 1) {
            const float uAp = __shfl_up(sAp, (unsigned)d, 64);
            const float uAq = __shfl_up(sAq, (unsigned)d, 64);
            const float uBp = __shfl_up(sBp, (unsigned)d, 64);
            const float uBq = __shfl_up(sBq, (unsigned)d, 64);
            if (lane >= d) {
                sAp = fmaf(k0, uAp, sAp);
                sAq = fmaf(k1, uAq, sAq);
                sBp = fmaf(k0, uBp, sBp);
                sBq = fmaf(k1, uBq, sBq);
            }
            k0 *= k0;
            k1 *= k1;
        }
        float eAp = __shfl_up(sAp, 1u, 64);
        float eAq = __shfl_up(sAq, 1u, 64);
        float eBp = __shfl_up(sBp, 1u, 64);
        float eBq = __shfl_up(sBq, 1u, 64);
        if (lane == 0) { eAp = eAq = eBp = eBq = 0.0f; }

        // ---- cross-wave exchange: per-row slots, lgkm-only drain barrier ----
        if (lane == 63) {
            ctot[r][0][w]     = sAp;  ctot[r][1][w]     = sAq;
            ctot[r][0][4 + w] = sBp;  ctot[r][1][4 + w] = sBq;
        }
        asm volatile("s_waitcnt lgkmcnt(0)" ::: "memory");
        __builtin_amdgcn_s_barrier();   // global prefetches stay in flight

        float GAp = 0.0f, GAq = 0.0f;   // carry into chunk w
#pragma unroll
        for (int d = 0; d < 3; ++d) {
            if (d < w) {
                GAp = fmaf(A256_0, GAp, ctot[r][0][d]);
                GAq = fmaf(A256_1, GAq, ctot[r][1][d]);
            }
        }
        float GBp = 0.0f, GBq = 0.0f;   // carry into chunk 4+w
#pragma unroll
        for (int d = 0; d < 7; ++d) {
            if (d < 4 + w) {
                GBp = fmaf(A256_0, GBp, ctot[r][0][d]);
                GBq = fmaf(A256_1, GBq, ctot[r][1][d]);
            }
        }
        const float cinAp = fmaf(GAp, pw0l, eAp);
        const float cinAq = fmaf(GAq, pw1l, eAq);
        const float cinBp = fmaf(GBp, pw0l, eBp);
        const float cinBq = fmaf(GBq, pw1l, eBq);

        // ---- pass 2: recompute seeded with carry, fused epilogue ----
        f4 yA, yB;
        {
            float p = cinAp, q = cinAq;
#pragma unroll
            for (int j = 0; j < 4; ++j) {
                p = fmaf(dv0, p, cxA[j] * wA[j]);
                q = fmaf(dv1, q, cxA[j]);
                yA[j] = fmaf(vA[j], q, p) + bA[j];
            }
        }
        {
            float p = cinBp, q = cinBq;
#pragma unroll
            for (int j = 0; j < 4; ++j) {
                p = fmaf(dv0, p, cxB[j] * wB[j]);
                q = fmaf(dv1, q, cxB[j]);
                yB[j] = fmaf(vB[j], q, p) + bB[j];
            }
        }

        long rs = row0 + r; if (rs >= nrows) rs = nrows - 1;
        f4* o4 = (f4*)(out + rs * (long)S_LEN);
        o4[sA] = yA;
        o4[sB] = yB;

        // ---- rotate pipeline buffers (SSA, compile-time after unroll) ----
        cxA = nxA; cxB = nxB;
        if (r + 2 < RPB) { nxA = pxA; nxB = pxB; }
    }
}

extern "C" void kernel_launch(void* const* d_in, const int* in_sizes, int n_in,
                              void* d_out, int out_size, void* d_ws, size_t ws_size,
                              hipStream_t stream) {
    const float* x      = (const float*)d_in[0];
    const float* weight = (const float*)d_in[1];
    const float* bias   = (const float*)d_in[2];
    const float* decay  = (const float*)d_in[3];
    float* out = (float*)d_out;

    const int nrows   = in_sizes[0] / S_LEN;      // B*E = 8192
    const int nblocks = (nrows + RPB - 1) / RPB;  // 2048
    hipLaunchKernelGGL(crcl_kernel, dim3(nblocks), dim3(THREADS), 0, stream,
                       x, weight, bias, decay, out, nrows);
}